// Round 4
// baseline (1540980.762 us; speedup 1.0000x reference)
//
#include <hip/hip_runtime.h>
#include <hip/hip_fp16.h>
#include <math.h>

typedef unsigned int  uint32;
typedef unsigned short u16;

#define NWG 65          // 1 sequential WG + 64 helper WGs
#define NTH 512

// workspace layout (bytes)
#define OFF_XP   1024u                        // xp buffer [256][768] f32
#define OFF_XC   (OFF_XP + 256u*768u*4u)      // Xc / seq / Xr buffer [256][256] f32
#define OFF_D    (OFF_XC + 256u*256u*4u)      // dec_out row buffer [256][256] f32
#define OFF_Y1   (OFF_D  + 256u*256u*4u)      // y1 [128][512] f32

typedef _Float16 half2_t __attribute__((ext_vector_type(2)));
typedef uint32 u32x16 __attribute__((ext_vector_type(16)));   // 16 packed f16-pairs

__device__ __forceinline__ float fdot2f(uint32 w, uint32 h, float acc) {
#if __has_builtin(__builtin_amdgcn_fdot2)
  return __builtin_amdgcn_fdot2(__builtin_bit_cast(half2_t, w),
                                __builtin_bit_cast(half2_t, h), acc, false);
#else
  half2_t a = __builtin_bit_cast(half2_t, w);
  half2_t b = __builtin_bit_cast(half2_t, h);
  return acc + (float)a[0]*(float)b[0] + (float)a[1]*(float)b[1];
#endif
}

__device__ __forceinline__ uint32 pack_h2(float x, float y) {
  _Float16 hx = (_Float16)x, hy = (_Float16)y;
  u16 ux = __builtin_bit_cast(u16, hx);
  u16 uy = __builtin_bit_cast(u16, hy);
  return (uint32)ux | ((uint32)uy << 16);
}

// pack 32 consecutive f32 weights into one u32x16 of f16 pairs (SSA value)
__device__ __forceinline__ u32x16 pack16(const float* __restrict__ p) {
  u32x16 v;
#pragma unroll
  for (int q = 0; q < 16; ++q) v[q] = pack_h2(p[2*q], p[2*q+1]);
  return v;
}

__device__ __forceinline__ float sigm(float x) { return 1.0f/(1.0f + expf(-x)); }

// 4 dot2s against one uint4 of h (8 f16 values)
#define D4(W, k, hpw, A) \
  A##0 = fdot2f(W[(k)+0], hpw.x, A##0); A##1 = fdot2f(W[(k)+1], hpw.y, A##1); \
  A##0 = fdot2f(W[(k)+2], hpw.z, A##0); A##1 = fdot2f(W[(k)+3], hpw.w, A##1);

// one 64-h-value chunk: full-row dots always; half-row dots for one class
#define CHUNK(WF, WH, HALFCLS, base) { \
    uint4 hpa = h4[(base)+0], hpb = h4[(base)+1]; \
    uint4 hpc = h4[(base)+2], hpd = h4[(base)+3]; \
    D4(WF, 0, hpa, a) D4(WF, 4, hpb, a) D4(WF, 8, hpc, a) D4(WF, 12, hpd, a) \
    if (cls == (HALFCLS)) { \
      D4(WH, 0, hpa, b) D4(WH, 4, hpb, b) D4(WH, 8, hpc, b) D4(WH, 12, hpd, b) \
    } }

// 256 sequential GRU cells. Weights live in 12 u32x16 SSA vectors (192 VGPRs).
// lane (cls=0, i): full row r_i (wf0..7) + n_i[0:128]   (wh0..3, h chunks 0-3)
// lane (cls=1, i): full row z_i (wf0..7) + n_i[128:256] (wh0..3, h chunks 4-7)
template<bool RELU>
__device__ __forceinline__ void run_cells(
    const float* __restrict__ xp, float* __restrict__ dst,
    const u32x16& wf0, const u32x16& wf1, const u32x16& wf2, const u32x16& wf3,
    const u32x16& wf4, const u32x16& wf5, const u32x16& wf6, const u32x16& wf7,
    const u32x16& wh0, const u32x16& wh1, const u32x16& wh2, const u32x16& wh3,
    float bfull, float bhalfn, float& h_reg, int i, int cls,
    u16* h16s, float* zbuf, float* nbuf)
{
  const uint4* h4 = (const uint4*)h16s;
  for (int t = 0; t < 256; ++t) {
    const float* xpt = xp + t * 768;
    float xA = (cls == 0) ? xpt[i] : xpt[256 + i];       // xr or xz (b_ih folded in)
    float xB = (cls == 0) ? xpt[512 + i] : 0.0f;         // xn (cls0 only)
    float a0 = 0.f, a1 = 0.f, b0 = 0.f, b1 = 0.f;
    CHUNK(wf0, wh0, 0, 0)   CHUNK(wf1, wh1, 0, 4)
    CHUNK(wf2, wh2, 0, 8)   CHUNK(wf3, wh3, 0, 12)
    CHUNK(wf4, wh0, 1, 16)  CHUNK(wf5, wh1, 1, 20)
    CHUNK(wf6, wh2, 1, 24)  CHUNK(wf7, wh3, 1, 28)
    float gfull = a0 + a1 + bfull;   // Wr·h+br (cls0) | Wz·h+bz (cls1)
    float ghalf = b0 + b1;           // partial Wn·h
    if (cls) {
      zbuf[i] = sigm(xA + gfull);    // z_i
      nbuf[i] = ghalf;               // n partial (k=128..255)
    }
    __syncthreads();
    if (!cls) {
      float r    = sigm(xA + gfull);
      float hn   = ghalf + nbuf[i] + bhalfn;             // Wn·h + b_hh_n
      float n    = tanhf(xB + r * hn);
      float z    = zbuf[i];
      float hnew = (1.0f - z) * n + z * h_reg;
      h_reg = hnew;
      h16s[i] = __builtin_bit_cast(u16, (_Float16)hnew); // raw h for next cell
      dst[t * 256 + i] = RELU ? fmaxf(hnew, 0.0f) : hnew;
    }
    __syncthreads();
  }
}

// helper-WG input projection: xpo[t][o] = sum_k src[t][k]*wih[o][k] + bih[o]
__device__ __forceinline__ void xp_gemm(
    const float* __restrict__ src, const float* __restrict__ wih,
    const float* __restrict__ bih, float* __restrict__ xpo,
    int wgi, int tid, float (&XcL)[4][256])
{
  const int t0 = wgi * 4;
  for (int r = tid; r < 1024; r += NTH) XcL[r >> 8][r & 255] = src[t0 * 256 + r];
  __syncthreads();
  for (int o = tid; o < 768; o += NTH) {
    const float* wr = wih + o * 256;
    float a0 = 0.f, a1 = 0.f, a2 = 0.f, a3 = 0.f;
#pragma unroll 4
    for (int k = 0; k < 256; ++k) {
      float w = wr[k];
      a0 += w * XcL[0][k]; a1 += w * XcL[1][k];
      a2 += w * XcL[2][k]; a3 += w * XcL[3][k];
    }
    float b = bih[o];
    xpo[(t0+0)*768+o] = a0+b; xpo[(t0+1)*768+o] = a1+b;
    xpo[(t0+2)*768+o] = a2+b; xpo[(t0+3)*768+o] = a3+b;
  }
  __syncthreads();
}

extern "C" __global__ void __launch_bounds__(NTH)
__attribute__((amdgpu_waves_per_eu(2, 2)))   // pin 2 waves/SIMD -> 256-VGPR budget
sed_kernel(const float* __restrict__ X,    const float* __restrict__ w1,
           const float* __restrict__ b1,   const float* __restrict__ w2,
           const float* __restrict__ b2,
           const float* __restrict__ ewih, const float* __restrict__ ewhh,
           const float* __restrict__ ebih, const float* __restrict__ ebhh,
           const float* __restrict__ dwih, const float* __restrict__ dwhh,
           const float* __restrict__ dbih, const float* __restrict__ dbhh,
           const float* __restrict__ fcw,  const float* __restrict__ fcb,
           float* __restrict__ out, unsigned char* __restrict__ ws)
{
  const int tid = threadIdx.x;
  const int wg  = blockIdx.x;
  uint32* bar_cnt = (uint32*)(ws);
  uint32* bar_rel = (uint32*)(ws + 128);
  float* xp = (float*)(ws + OFF_XP);
  float* Xc = (float*)(ws + OFF_XC);
  float* D  = (float*)(ws + OFF_D);
  float* y1 = (float*)(ws + OFF_Y1);

  __shared__ __align__(16) u16 h16s[256];
  __shared__ float zbuf[256], nbuf[256];
  __shared__ float XcL[4][256];
  __shared__ float hv[256], red[256], abuf[256], cbuf[256], pbuf[512];
  __shared__ float lbuf[26*8], la[32];

  unsigned round_ = 0;
  auto gbar = [&]() {
    __syncthreads();
    if (tid == 0) {
      unsigned old = __hip_atomic_fetch_add(bar_cnt, 1u, __ATOMIC_ACQ_REL,
                                            __HIP_MEMORY_SCOPE_AGENT);
      unsigned tgt = (round_ + 1u) * (unsigned)NWG;
      if (old + 1u == tgt)
        __hip_atomic_store(bar_rel, round_ + 1u, __ATOMIC_RELEASE,
                           __HIP_MEMORY_SCOPE_AGENT);
      while (__hip_atomic_load(bar_rel, __ATOMIC_ACQUIRE,
                               __HIP_MEMORY_SCOPE_AGENT) < round_ + 1u)
        __builtin_amdgcn_s_sleep(2);
    }
    round_ += 1u;
    __syncthreads();
  };

  const int i   = tid & 255;
  const int cls = tid >> 8;
  // weight registers (SSA vectors; no allocas)
  u32x16 wf0{}, wf1{}, wf2{}, wf3{}, wf4{}, wf5{}, wf6{}, wf7{};
  u32x16 wh0{}, wh1{}, wh2{}, wh3{};
  float bfull = 0.f, bhalfn = 0.f, h_reg = 0.f;

  // ---- P0a: y1[j][c] = w1[j]*x[c] + b1[j]   [128][512]
  for (int idx = wg * NTH + tid; idx < 128 * 512; idx += NWG * NTH) {
    int j = idx >> 9, c = idx & 511;
    y1[idx] = w1[j] * X[c] + b1[j];
  }
  gbar();

  // ---- P0b: seq[t][d] = y2[d][2t] (only even cols of y2 needed)
  for (int idx = wg * NTH + tid; idx < 256 * 256; idx += NWG * NTH) {
    int d = idx & 255, t = idx >> 8;
    const float* w2r = w2 + d * 128;
    float acc = b2[d];
#pragma unroll 4
    for (int j = 0; j < 128; ++j) acc += w2r[j] * y1[j * 512 + 2 * t];
    Xc[t * 256 + d] = acc;
  }
  gbar();

  // ---- P0c: helpers xp_enc = seq @ ewih^T + ebih ; WG0 loads enc W_hh regs
  if (wg == 0) {
    const int rfull = (cls == 0) ? i : (256 + i);
    const float* wr = ewhh + rfull * 256;
    wf0 = pack16(wr);        wf1 = pack16(wr + 32);
    wf2 = pack16(wr + 64);   wf3 = pack16(wr + 96);
    wf4 = pack16(wr + 128);  wf5 = pack16(wr + 160);
    wf6 = pack16(wr + 192);  wf7 = pack16(wr + 224);
    const float* wn = ewhh + (512 + i) * 256 + cls * 128;
    wh0 = pack16(wn);        wh1 = pack16(wn + 32);
    wh2 = pack16(wn + 64);   wh3 = pack16(wn + 96);
    bfull  = ebhh[rfull];
    bhalfn = (cls == 0) ? ebhh[512 + i] : 0.0f;
  } else {
    xp_gemm(Xc, ewih, ebih, xp, wg - 1, tid, XcL);
  }
  gbar();

  // ---- P1: encoder (256 cells), writes relu(h) into Xc (=Xr)
  if (wg == 0) {
    if (tid < 256) h16s[tid] = 0;
    h_reg = 0.f;
    __syncthreads();
    run_cells<true>(xp, Xc, wf0,wf1,wf2,wf3,wf4,wf5,wf6,wf7, wh0,wh1,wh2,wh3,
                    bfull, bhalfn, h_reg, i, cls, h16s, zbuf, nbuf);
  }
  gbar();

  // ---- P2: helpers xp^0 = Xr @ dwih^T + dbih ; WG0 loads dec W_hh regs
  if (wg == 0) {
    const int rfull = (cls == 0) ? i : (256 + i);
    const float* wr = dwhh + rfull * 256;
    wf0 = pack16(wr);        wf1 = pack16(wr + 32);
    wf2 = pack16(wr + 64);   wf3 = pack16(wr + 96);
    wf4 = pack16(wr + 128);  wf5 = pack16(wr + 160);
    wf6 = pack16(wr + 192);  wf7 = pack16(wr + 224);
    const float* wn = dwhh + (512 + i) * 256 + cls * 128;
    wh0 = pack16(wn);        wh1 = pack16(wn + 32);
    wh2 = pack16(wn + 64);   wh3 = pack16(wn + 96);
    bfull  = dbhh[rfull];
    bhalfn = (cls == 0) ? dbhh[512 + i] : 0.0f;
  } else {
    xp_gemm(Xc, dwih, dbih, xp, wg - 1, tid, XcL);
  }
  gbar();

  // ---- decoder: 256 outer rows
  for (int k = 0; k < 256; ++k) {
    // phase 1: WG0 runs the 256 sequential cells of row k (h carries across rows)
    if (wg == 0)
      run_cells<false>(xp, D, wf0,wf1,wf2,wf3,wf4,wf5,wf6,wf7, wh0,wh1,wh2,wh3,
                       bfull, bhalfn, h_reg, i, cls, h16s, zbuf, nbuf);
    gbar();

    // phase 2: helpers build xp^{k+1} from D; WG0 does attention + output row k
    if (wg == 0) {
      // h_new vector
      if (tid < 256) hv[tid] = D[255 * 256 + tid];
      __syncthreads();
      // s_t = D[t,:]·h_new  (split each dot across 2 threads)
      {
        int t = tid & 255, hh = tid >> 8;
        const float* dr  = D + t * 256 + hh * 128;
        const float* hvp = hv + hh * 128;
        float p = 0.f;
#pragma unroll 4
        for (int q = 0; q < 128; ++q) p += dr[q] * hvp[q];
        pbuf[hh * 256 + t] = p;
      }
      __syncthreads();
      if (tid < 256) { float s = pbuf[tid] + pbuf[256 + tid]; pbuf[tid] = s; red[tid] = s; }
      __syncthreads();
      for (int st = 128; st > 0; st >>= 1) {
        if (tid < st) red[tid] = fmaxf(red[tid], red[tid + st]);
        __syncthreads();
      }
      float m = red[0];
      __syncthreads();
      if (tid < 256) { float e = expf(pbuf[tid] - m); abuf[tid] = e; red[tid] = e; }
      __syncthreads();
      for (int st = 128; st > 0; st >>= 1) {
        if (tid < st) red[tid] += red[tid + st];
        __syncthreads();
      }
      float inv = 1.0f / red[0];
      __syncthreads();
      if (tid < 256) abuf[tid] *= inv;
      __syncthreads();
      // c[i] = a[0]*D[0,i] + sum_{t=1..255} a[t-1]*D[t,i]
      if (tid < 256) {
        float acc = abuf[0] * D[tid];
        for (int t = 1; t < 256; ++t) acc += abuf[t - 1] * D[t * 256 + tid];
        cbuf[tid] = acc;
      }
      __syncthreads();
      // logits: fc_w @ [h_new, c] + fc_b  (26 outputs, 8 partials each)
      if (tid < 26 * 8) {
        int j = tid >> 3, sgm = tid & 7;
        const float* fr   = fcw + j * 512 + sgm * 64;
        const float* vsrc = (sgm < 4) ? (hv + sgm * 64) : (cbuf + (sgm - 4) * 64);
        float p = 0.f;
#pragma unroll 4
        for (int q = 0; q < 64; ++q) p += fr[q] * vsrc[q];
        lbuf[tid] = p;
      }
      __syncthreads();
      if (tid < 26) {
        float l = fcb[tid];
#pragma unroll
        for (int s = 0; s < 8; ++s) l += lbuf[tid * 8 + s];
        la[tid] = l;
      }
      __syncthreads();
      if (tid == 0) {
        float m2 = la[0];
        for (int j = 1; j < 26; ++j) m2 = fmaxf(m2, la[j]);
        float sm = 0.f;
        for (int j = 0; j < 26; ++j) { float e = expf(la[j] - m2); la[j] = e; sm += e; }
        float ii = 1.0f / sm;
        for (int j = 0; j < 26; ++j) la[j] *= ii;
      }
      __syncthreads();
      if (tid < 26) out[k * 26 + tid] = la[tid];
      __syncthreads();
    } else if (k < 255) {
      xp_gemm(D, dwih, dbih, xp, wg - 1, tid, XcL);
    }
    gbar();
  }
}

extern "C" void kernel_launch(void* const* d_in, const int* in_sizes, int n_in,
                              void* d_out, int out_size, void* d_ws, size_t ws_size,
                              hipStream_t stream) {
  (void)in_sizes; (void)n_in; (void)out_size; (void)ws_size;
  // zero the grid-barrier counters (ws is poisoned 0xAA before every launch)
  hipMemsetAsync(d_ws, 0, 1024, stream);
  sed_kernel<<<NWG, NTH, 0, stream>>>(
      (const float*)d_in[0],  (const float*)d_in[1],  (const float*)d_in[2],
      (const float*)d_in[3],  (const float*)d_in[4],  (const float*)d_in[5],
      (const float*)d_in[6],  (const float*)d_in[7],  (const float*)d_in[8],
      (const float*)d_in[9],  (const float*)d_in[10], (const float*)d_in[11],
      (const float*)d_in[12], (const float*)d_in[13], (const float*)d_in[14],
      (float*)d_out, (unsigned char*)d_ws);
}

// Round 5
// 125576.514 us; speedup vs baseline: 12.2712x; 12.2712x over previous
//
#include <hip/hip_runtime.h>
#include <hip/hip_fp16.h>
#include <math.h>

typedef unsigned int  uint32;
typedef unsigned short u16;

#define NWG 65          // 1 sequential WG + 64 helper WGs
#define NTH 512         // 8 waves

// workspace layout (bytes)
#define OFF_XP   1024u                        // xp buffer [256][768] f32
#define OFF_XC   (OFF_XP + 256u*768u*4u)      // Xc / seq / Xr buffer [256][256] f32
#define OFF_D    (OFF_XC + 256u*256u*4u)      // dec_out row buffer [256][256] f32
#define OFF_Y1   (OFF_D  + 256u*256u*4u)      // y1 [128][512] f32

typedef _Float16 f16x8 __attribute__((ext_vector_type(8)));
typedef float    f32x4 __attribute__((ext_vector_type(4)));

__device__ __forceinline__ float sigm(float x) { return 1.0f/(1.0f + expf(-x)); }

// convert 8 consecutive f32 weights to one MFMA A-fragment quarter (f16x8)
__device__ __forceinline__ f16x8 ldfrag(const float* __restrict__ p) {
  f16x8 v;
#pragma unroll
  for (int j = 0; j < 8; ++j) v[j] = (_Float16)p[j];
  return v;
}

// 48 A-fragments per lane: fr_m_ks = W[96*W + 16*m + (l&15)][32*ks + (l>>4)*8 .. +7]
#define FRAG_ALL(OP) \
  OP(0,0) OP(0,1) OP(0,2) OP(0,3) OP(0,4) OP(0,5) OP(0,6) OP(0,7) \
  OP(1,0) OP(1,1) OP(1,2) OP(1,3) OP(1,4) OP(1,5) OP(1,6) OP(1,7) \
  OP(2,0) OP(2,1) OP(2,2) OP(2,3) OP(2,4) OP(2,5) OP(2,6) OP(2,7) \
  OP(3,0) OP(3,1) OP(3,2) OP(3,3) OP(3,4) OP(3,5) OP(3,6) OP(3,7) \
  OP(4,0) OP(4,1) OP(4,2) OP(4,3) OP(4,4) OP(4,5) OP(4,6) OP(4,7) \
  OP(5,0) OP(5,1) OP(5,2) OP(5,3) OP(5,4) OP(5,5) OP(5,6) OP(5,7)

#define DECLF(m,ks) f16x8 fr_##m##_##ks{};
#define LOADF(m,ks) fr_##m##_##ks = ldfrag(whp + (96*W + 16*(m) + rloc)*256 + 32*(ks) + ko8);
#define MFK(m,ks)   acc##m = __builtin_amdgcn_mfma_f32_16x16x32_f16(fr_##m##_##ks, Bf, acc##m, 0, 0, 0);
#define KSBLK(ks)   { f16x8 Bf = __builtin_bit_cast(f16x8, h4[(ks)*4 + kg]); \
                      MFK(0,ks) MFK(1,ks) MFK(2,ks) MFK(3,ks) MFK(4,ks) MFK(5,ks) }

// helper-WG input projection: xpo[t][o] = sum_k src[t][k]*wih[o][k] + bih[o]
__device__ __forceinline__ void xp_gemm(
    const float* __restrict__ src, const float* __restrict__ wih,
    const float* __restrict__ bih, float* __restrict__ xpo,
    int wgi, int tid, float (&XcL)[4][256])
{
  const int t0 = wgi * 4;
  for (int r = tid; r < 1024; r += NTH) XcL[r >> 8][r & 255] = src[t0 * 256 + r];
  __syncthreads();
  for (int o = tid; o < 768; o += NTH) {
    const float* wr = wih + o * 256;
    float a0 = 0.f, a1 = 0.f, a2 = 0.f, a3 = 0.f;
#pragma unroll 4
    for (int k = 0; k < 256; ++k) {
      float w = wr[k];
      a0 += w * XcL[0][k]; a1 += w * XcL[1][k];
      a2 += w * XcL[2][k]; a3 += w * XcL[3][k];
    }
    float b = bih[o];
    xpo[(t0+0)*768+o] = a0+b; xpo[(t0+1)*768+o] = a1+b;
    xpo[(t0+2)*768+o] = a2+b; xpo[(t0+3)*768+o] = a3+b;
  }
  __syncthreads();
}

extern "C" __global__ void __launch_bounds__(NTH)
__attribute__((amdgpu_waves_per_eu(2, 2)))   // 2 waves/SIMD -> 256 unified regs/wave
sed_kernel(const float* __restrict__ X,    const float* __restrict__ w1,
           const float* __restrict__ b1,   const float* __restrict__ w2,
           const float* __restrict__ b2,
           const float* __restrict__ ewih, const float* __restrict__ ewhh,
           const float* __restrict__ ebih, const float* __restrict__ ebhh,
           const float* __restrict__ dwih, const float* __restrict__ dwhh,
           const float* __restrict__ dbih, const float* __restrict__ dbhh,
           const float* __restrict__ fcw,  const float* __restrict__ fcb,
           float* __restrict__ out, unsigned char* __restrict__ ws)
{
  const int tid = threadIdx.x;
  const int wg  = blockIdx.x;
  uint32* bar_cnt = (uint32*)(ws);
  uint32* bar_rel = (uint32*)(ws + 128);
  float* xp = (float*)(ws + OFF_XP);
  float* Xc = (float*)(ws + OFF_XC);
  float* D  = (float*)(ws + OFF_D);
  float* y1 = (float*)(ws + OFF_Y1);

  __shared__ __align__(16) u16 h16s[256];      // h as f16, k-major
  __shared__ __align__(16) float gbuf[768];    // W_hh·h pre-activations
  __shared__ float bbuf[768];                  // b_hh
  __shared__ float XcL[4][256];
  __shared__ float hv[256], red[256], abuf[256], cbuf[256], pbuf[512];
  __shared__ float lbuf[26*8], la[32];

  unsigned round_ = 0;
  auto gbar = [&]() {
    __syncthreads();
    if (tid == 0) {
      unsigned old = __hip_atomic_fetch_add(bar_cnt, 1u, __ATOMIC_ACQ_REL,
                                            __HIP_MEMORY_SCOPE_AGENT);
      unsigned tgt = (round_ + 1u) * (unsigned)NWG;
      if (old + 1u == tgt)
        __hip_atomic_store(bar_rel, round_ + 1u, __ATOMIC_RELEASE,
                           __HIP_MEMORY_SCOPE_AGENT);
      while (__hip_atomic_load(bar_rel, __ATOMIC_ACQUIRE,
                               __HIP_MEMORY_SCOPE_AGENT) < round_ + 1u)
        __builtin_amdgcn_s_sleep(2);
    }
    round_ += 1u;
    __syncthreads();
  };

  const int l    = tid & 63;        // lane
  const int W    = tid >> 6;        // wave 0..7 -> rows 96W..96W+95
  const int rloc = l & 15;          // A row within 16-row tile
  const int kg   = l >> 4;          // k-group 0..3 (8 k each)
  const int ko8  = kg * 8;

  FRAG_ALL(DECLF)                   // 48 f16x8 weight fragments (192 regs)
  float h_reg = 0.f;

  auto loadW = [&](const float* __restrict__ whp, const float* __restrict__ bhh) {
    FRAG_ALL(LOADF)
    for (int idx = tid; idx < 768; idx += NTH) bbuf[idx] = bhh[idx];
  };

  // 256 sequential GRU cells: MFMA matvec (all 8 waves) + h_new (threads<256)
  auto cells = [&](const float* __restrict__ xpb, float* __restrict__ dst,
                   bool relu) {
    const uint4* h4 = (const uint4*)h16s;
    for (int t = 0; t < 256; ++t) {
      const float* xpt = xpb + t * 768;
      float xr = 0.f, xz = 0.f, xn = 0.f;
      if (tid < 256) {               // prefetch xp early; consumed after barrier
        xr = xpt[tid]; xz = xpt[256 + tid]; xn = xpt[512 + tid];
      }
      f32x4 acc0{}, acc1{}, acc2{}, acc3{}, acc4{}, acc5{};
      KSBLK(0) KSBLK(1) KSBLK(2) KSBLK(3)
      KSBLK(4) KSBLK(5) KSBLK(6) KSBLK(7)
      if (rloc == 0) {               // D col 0: rows (l>>4)*4+j of each tile
        *(f32x4*)(gbuf + 96*W + 16*0 + kg*4) = acc0;
        *(f32x4*)(gbuf + 96*W + 16*1 + kg*4) = acc1;
        *(f32x4*)(gbuf + 96*W + 16*2 + kg*4) = acc2;
        *(f32x4*)(gbuf + 96*W + 16*3 + kg*4) = acc3;
        *(f32x4*)(gbuf + 96*W + 16*4 + kg*4) = acc4;
        *(f32x4*)(gbuf + 96*W + 16*5 + kg*4) = acc5;
      }
      __syncthreads();               // gbuf ready; all h16s reads done
      if (tid < 256) {
        float r    = sigm(xr + gbuf[tid]       + bbuf[tid]);
        float z    = sigm(xz + gbuf[256 + tid] + bbuf[256 + tid]);
        float n    = tanhf(xn + r * (gbuf[512 + tid] + bbuf[512 + tid]));
        float hnew = (1.0f - z) * n + z * h_reg;
        h_reg = hnew;
        h16s[tid] = __builtin_bit_cast(u16, (_Float16)hnew);
        dst[t * 256 + tid] = relu ? fmaxf(hnew, 0.0f) : hnew;
      }
      __syncthreads();               // new h visible
    }
  };

  // ---- P0a: y1[j][c] = w1[j]*x[c] + b1[j]   [128][512]
  for (int idx = wg * NTH + tid; idx < 128 * 512; idx += NWG * NTH) {
    int j = idx >> 9, c = idx & 511;
    y1[idx] = w1[j] * X[c] + b1[j];
  }
  gbar();

  // ---- P0b: seq[t][d] = y2[d][2t] (only even cols of y2 needed)
  for (int idx = wg * NTH + tid; idx < 256 * 256; idx += NWG * NTH) {
    int d = idx & 255, t = idx >> 8;
    const float* w2r = w2 + d * 128;
    float acc = b2[d];
#pragma unroll 4
    for (int j = 0; j < 128; ++j) acc += w2r[j] * y1[j * 512 + 2 * t];
    Xc[t * 256 + d] = acc;
  }
  gbar();

  // ---- P0c: helpers xp_enc = seq @ ewih^T + ebih ; WG0 loads enc W_hh frags
  if (wg == 0) loadW(ewhh, ebhh);
  else         xp_gemm(Xc, ewih, ebih, xp, wg - 1, tid, XcL);
  gbar();

  // ---- P1: encoder (256 cells), writes relu(h) into Xc (=Xr)
  if (wg == 0) {
    if (tid < 256) h16s[tid] = 0;
    h_reg = 0.f;
    __syncthreads();
    cells(xp, Xc, true);
  }
  gbar();

  // ---- P2: helpers xp^0 = Xr @ dwih^T + dbih ; WG0 loads dec W_hh frags
  if (wg == 0) loadW(dwhh, dbhh);
  else         xp_gemm(Xc, dwih, dbih, xp, wg - 1, tid, XcL);
  gbar();

  // ---- decoder: 256 outer rows
  for (int k = 0; k < 256; ++k) {
    // phase 1: WG0 runs the 256 sequential cells of row k (h carries across rows)
    if (wg == 0) cells(xp, D, false);
    gbar();

    // phase 2: helpers build xp^{k+1} from D; WG0 does attention + output row k
    if (wg == 0) {
      // h_new vector
      if (tid < 256) hv[tid] = D[255 * 256 + tid];
      __syncthreads();
      // s_t = D[t,:]·h_new  (split each dot across 2 threads)
      {
        int t = tid & 255, hh = tid >> 8;
        const float* dr  = D + t * 256 + hh * 128;
        const float* hvp = hv + hh * 128;
        float p = 0.f;
#pragma unroll 4
        for (int q = 0; q < 128; ++q) p += dr[q] * hvp[q];
        pbuf[hh * 256 + t] = p;
      }
      __syncthreads();
      if (tid < 256) { float s = pbuf[tid] + pbuf[256 + tid]; pbuf[tid] = s; red[tid] = s; }
      __syncthreads();
      for (int st = 128; st > 0; st >>= 1) {
        if (tid < st) red[tid] = fmaxf(red[tid], red[tid + st]);
        __syncthreads();
      }
      float m = red[0];
      __syncthreads();
      if (tid < 256) { float e = expf(pbuf[tid] - m); abuf[tid] = e; red[tid] = e; }
      __syncthreads();
      for (int st = 128; st > 0; st >>= 1) {
        if (tid < st) red[tid] += red[tid + st];
        __syncthreads();
      }
      float inv = 1.0f / red[0];
      __syncthreads();
      if (tid < 256) abuf[tid] *= inv;
      __syncthreads();
      // c[i] = a[0]*D[0,i] + sum_{t=1..255} a[t-1]*D[t,i]
      if (tid < 256) {
        float acc = abuf[0] * D[tid];
        for (int t = 1; t < 256; ++t) acc += abuf[t - 1] * D[t * 256 + tid];
        cbuf[tid] = acc;
      }
      __syncthreads();
      // logits: fc_w @ [h_new, c] + fc_b  (26 outputs, 8 partials each)
      if (tid < 26 * 8) {
        int j = tid >> 3, sgm = tid & 7;
        const float* fr   = fcw + j * 512 + sgm * 64;
        const float* vsrc = (sgm < 4) ? (hv + sgm * 64) : (cbuf + (sgm - 4) * 64);
        float p = 0.f;
#pragma unroll 4
        for (int q = 0; q < 64; ++q) p += fr[q] * vsrc[q];
        lbuf[tid] = p;
      }
      __syncthreads();
      if (tid < 26) {
        float lgt = fcb[tid];
#pragma unroll
        for (int s = 0; s < 8; ++s) lgt += lbuf[tid * 8 + s];
        la[tid] = lgt;
      }
      __syncthreads();
      if (tid == 0) {
        float m2 = la[0];
        for (int j = 1; j < 26; ++j) m2 = fmaxf(m2, la[j]);
        float sm = 0.f;
        for (int j = 0; j < 26; ++j) { float e = expf(la[j] - m2); la[j] = e; sm += e; }
        float ii = 1.0f / sm;
        for (int j = 0; j < 26; ++j) la[j] *= ii;
      }
      __syncthreads();
      if (tid < 26) out[k * 26 + tid] = la[tid];
      __syncthreads();
    } else if (k < 255) {
      xp_gemm(D, dwih, dbih, xp, wg - 1, tid, XcL);
    }
    gbar();
  }
}

extern "C" void kernel_launch(void* const* d_in, const int* in_sizes, int n_in,
                              void* d_out, int out_size, void* d_ws, size_t ws_size,
                              hipStream_t stream) {
  (void)in_sizes; (void)n_in; (void)out_size; (void)ws_size;
  // zero the grid-barrier counters (ws is poisoned 0xAA before every launch)
  hipMemsetAsync(d_ws, 0, 1024, stream);
  sed_kernel<<<NWG, NTH, 0, stream>>>(
      (const float*)d_in[0],  (const float*)d_in[1],  (const float*)d_in[2],
      (const float*)d_in[3],  (const float*)d_in[4],  (const float*)d_in[5],
      (const float*)d_in[6],  (const float*)d_in[7],  (const float*)d_in[8],
      (const float*)d_in[9],  (const float*)d_in[10], (const float*)d_in[11],
      (const float*)d_in[12], (const float*)d_in[13], (const float*)d_in[14],
      (float*)d_out, (unsigned char*)d_ws);
}